// Round 1
// 193.328 us; speedup vs baseline: 1.0317x; 1.0317x over previous
//
#include <hip/hip_runtime.h>
#include <stdint.h>

typedef __bf16 bf16;
typedef __bf16 bf16x8 __attribute__((ext_vector_type(8)));
typedef __bf16 bf16x4 __attribute__((ext_vector_type(4)));
typedef float  f32x4  __attribute__((ext_vector_type(4)));
typedef unsigned int u32;

#define E_DIM 1024
#define S_LEN 2048
#define BATCH 2
#define NH 16
#define DH 64

#define NEG_INF (-__builtin_inff())

union BU { u32 u[4]; bf16x8 h; };

__device__ __forceinline__ u32 cvtpk_bf16(float lo, float hi) {
    u32 r;
    asm("v_cvt_pk_bf16_f32 %0, %1, %2" : "=v"(r) : "v"(lo), "v"(hi));
    return r;
}
// v_permlane32_swap_b32: a[32:63] <-> b[0:31]  (both operands read-write)
__device__ __forceinline__ void pswap32(u32 &a, u32 &b) {
    asm("v_permlane32_swap_b32 %0, %1" : "+v"(a), "+v"(b));
}
// v_permlane16_swap_b32: a[16:31]<->b[0:15], a[48:63]<->b[32:47]
__device__ __forceinline__ void pswap16(u32 &a, u32 &b) {
    asm("v_permlane16_swap_b32 %0, %1" : "+v"(a), "+v"(b));
}

// async global->LDS, 16B per lane; LDS dst = wave-uniform base + lane*16 (m104)
__device__ __forceinline__ void load_lds16(const bf16* g, bf16* l) {
    __builtin_amdgcn_global_load_lds(
        (const __attribute__((address_space(1))) void*)g,
        (__attribute__((address_space(3))) void*)l, 16, 0, 0);
}

// ---------------------------------------------------------------------------
// fp32 -> bf16 conversion for x, Wq, Wk, Wv, Wo
// ---------------------------------------------------------------------------
__global__ __launch_bounds__(256) void convert_kernel(
    const float* __restrict__ s0, const float* __restrict__ s1,
    const float* __restrict__ s2, const float* __restrict__ s3,
    const float* __restrict__ s4,
    bf16* __restrict__ d0, bf16* __restrict__ d1, bf16* __restrict__ d2,
    bf16* __restrict__ d3, bf16* __restrict__ d4,
    int n0, int n1)
{
    const float* src; bf16* dst; int n;
    switch (blockIdx.y) {
        case 0:  src = s0; dst = d0; n = n0; break;
        case 1:  src = s1; dst = d1; n = n1; break;
        case 2:  src = s2; dst = d2; n = n1; break;
        case 3:  src = s3; dst = d3; n = n1; break;
        default: src = s4; dst = d4; n = n1; break;
    }
    int i = (blockIdx.x * 256 + threadIdx.x) * 4;
    if (i >= n) return;
    float4 v = *(const float4*)(src + i);
    bf16x4 o;
    o[0] = (bf16)v.x; o[1] = (bf16)v.y; o[2] = (bf16)v.z; o[3] = (bf16)v.w;
    *(bf16x4*)(dst + i) = o;
}

// ---------------------------------------------------------------------------
// GEMM (unchanged structure): m97 width-16 async staging + single-barrier
// double buffer, BK=32. C = A * W^T + bias.
// mode-0 scale now 0.125*log2(e) so attention can use exp2 directly.
// ---------------------------------------------------------------------------
__global__ __launch_bounds__(256) void gemm_kernel(
    const bf16* __restrict__ A,
    const bf16* __restrict__ W0, const bf16* __restrict__ W1, const bf16* __restrict__ W2,
    const float* __restrict__ bias0, const float* __restrict__ bias1, const float* __restrict__ bias2,
    bf16* __restrict__ outQ, bf16* __restrict__ outK, bf16* __restrict__ outVt,
    float* __restrict__ outF, int final_mode)
{
    __shared__ bf16 As[2][128 * 32];
    __shared__ bf16 Bs[2][128 * 32];

    int mode;
    const bf16* W; const float* bias;
    if (final_mode) { mode = 3; W = W0; bias = bias0; }
    else {
        mode = blockIdx.z;
        W    = (mode == 0) ? W0 : (mode == 1 ? W1 : W2);
        bias = (mode == 0) ? bias0 : (mode == 1 ? bias1 : bias2);
    }

    const int bm = blockIdx.y * 128, bn = blockIdx.x * 128;
    const int t = threadIdx.x;
    const int lane = t & 63, w = t >> 6;
    const int quad = lane >> 4, l16 = lane & 15;
    const int wm = (w & 1) * 64, wn = (w >> 1) * 64;

    const int r0 = w * 16;
    const int srow = r0 + (lane >> 2), scol = (lane & 3) * 8;
    const bf16* Ag0 = A + (size_t)(bm + srow) * E_DIM + scol;
    const bf16* Ag1 = Ag0 + (size_t)64 * E_DIM;
    const bf16* Wg0 = W + (size_t)(bn + srow) * E_DIM + scol;
    const bf16* Wg1 = Wg0 + (size_t)64 * E_DIM;

    f32x4 acc[4][4];
#pragma unroll
    for (int i = 0; i < 4; i++)
#pragma unroll
        for (int j = 0; j < 4; j++) acc[i][j] = f32x4{0.f, 0.f, 0.f, 0.f};

    load_lds16(Ag0, As[0] + r0 * 32);
    load_lds16(Ag1, As[0] + (64 + r0) * 32);
    load_lds16(Wg0, Bs[0] + r0 * 32);
    load_lds16(Wg1, Bs[0] + (64 + r0) * 32);

    int cur = 0;
    for (int kt = 0; kt < E_DIM; kt += 32) {
        __syncthreads();

        if (kt + 32 < E_DIM) {
            const int nxt = cur ^ 1;
            load_lds16(Ag0 + kt + 32, As[nxt] + r0 * 32);
            load_lds16(Ag1 + kt + 32, As[nxt] + (64 + r0) * 32);
            load_lds16(Wg0 + kt + 32, Bs[nxt] + r0 * 32);
            load_lds16(Wg1 + kt + 32, Bs[nxt] + (64 + r0) * 32);
        }

        bf16x8 af[4], bfr[4];
#pragma unroll
        for (int i = 0; i < 4; i++)
            af[i] = *(const bf16x8*)(As[cur] + (wm + i * 16 + l16) * 32 + quad * 8);
#pragma unroll
        for (int j = 0; j < 4; j++)
            bfr[j] = *(const bf16x8*)(Bs[cur] + (wn + j * 16 + l16) * 32 + quad * 8);
#pragma unroll
        for (int i = 0; i < 4; i++)
#pragma unroll
            for (int j = 0; j < 4; j++)
                acc[i][j] = __builtin_amdgcn_mfma_f32_16x16x32_bf16(af[i], bfr[j], acc[i][j], 0, 0, 0);

        cur ^= 1;
    }

#pragma unroll
    for (int j = 0; j < 4; j++) {
        const int n = bn + wn + j * 16 + l16;
        const float bv = bias[n];
#pragma unroll
        for (int i = 0; i < 4; i++) {
            const int m0 = bm + wm + i * 16 + quad * 4;
            if (mode == 3) {
#pragma unroll
                for (int r = 0; r < 4; r++)
                    outF[(size_t)(m0 + r) * E_DIM + n] = acc[i][j][r] + bv;
            } else if (mode == 2) {
                const int b_ = m0 >> 11, s0 = m0 & (S_LEN - 1);
                const int h = n >> 6, d = n & 63;
                bf16x4 pv;
#pragma unroll
                for (int r = 0; r < 4; r++) pv[r] = (bf16)(acc[i][j][r] + bv);
                *(bf16x4*)(outVt + ((size_t)((b_ * NH + h) * DH + d)) * S_LEN + s0) = pv;
            } else {
                bf16* o = (mode == 0) ? outQ : outK;
                // Q pre-scaled by 0.125 * log2(e) so attn softmax uses exp2
                const float sc = (mode == 0) ? 0.18033688f : 1.0f;
                const int h = n >> 6, d = n & 63;
#pragma unroll
                for (int r = 0; r < 4; r++) {
                    const int m = m0 + r;
                    const int b_ = m >> 11, s = m & (S_LEN - 1);
                    o[((size_t)(b_ * NH + h) * S_LEN + s) * DH + d] = (bf16)((acc[i][j][r] + bv) * sc);
                }
            }
        }
    }
}

// ---------------------------------------------------------------------------
// Flash attention, causal — swapped-operand QK^T (S^T = mfma(K,Q)) so each
// lane owns its q-row's scores; softmax fully in registers; P -> PV B-frag
// via v_cvt_pk_bf16_f32 + permlane32/16_swap (no P LDS round-trip at all).
// 8 waves = 4 q-stripes(32q) x 2 k-halves: each wave reads only half of the
// K/V tiles from LDS while covering 32 q-rows -> LDS read traffic per
// 128x128 tile-product halves (128KB). Cross-k-half O/l reduction once at
// the epilogue through the freed LDS (P buffer is gone; LDS = 35KB).
// Grid 512 (one 128-q tile per block), qt = 15-qq / qq so dispatch pairs
// blocks i and i+256 on one CU with summed work 17 tiles -> 2 blocks/CU.
// Staging loads for tile kt+1 issue before compute of kt (T14).
// ---------------------------------------------------------------------------
__global__ __launch_bounds__(512, 4) void attn_kernel(
    const bf16* __restrict__ Qb, const bf16* __restrict__ Kb,
    const bf16* __restrict__ Vtb, bf16* __restrict__ Ob)
{
    __shared__ __align__(16) char smem[35840];
    bf16* Ks = (bf16*)smem;              // [128][72]  18.0 KB
    bf16* Vs = (bf16*)(smem + 18432);    // [64][136]  17.0 KB

    const int t = threadIdx.x, lane = t & 63, w = t >> 6;
    const int quad = lane >> 4, l16 = lane & 15;
    const int qs = w & 3, kh = w >> 2;   // q-stripe 0..3, k-half 0..1

    const int i = blockIdx.x;
    const int half = i >> 8, jj = i & 255;
    const int xcd = jj & 7, rr = jj >> 3;       // rr 0..31
    const int bh = (xcd << 2) | (rr & 3);       // 4 bh per XCD (L2-resident K/V)
    const int qq = rr >> 2;                     // 0..7
    const int qt = half ? qq : 15 - qq;         // pair (i, i+256): work sums to 17

    const bf16* Qg = Qb + (size_t)bh * S_LEN * DH;
    const bf16* Kg = Kb + (size_t)bh * S_LEN * DH;
    const bf16* Vg = Vtb + (size_t)bh * DH * S_LEN;
    const int b_ = bh >> 4, hh = bh & 15;
    bf16* Og = Ob + (size_t)b_ * S_LEN * E_DIM + hh * DH;

    const int qrow0 = qt * 128 + qs * 32;

    // Q B-fragments: lane = q-row (l16) of each 16-q stripe, cols d
    bf16x8 qf[2][2];
#pragma unroll
    for (int qh = 0; qh < 2; qh++) {
        const bf16* qp = Qg + (size_t)(qrow0 + qh * 16 + l16) * DH + quad * 8;
        qf[qh][0] = *(const bf16x8*)(qp);
        qf[qh][1] = *(const bf16x8*)(qp + 32);
    }

    f32x4 o[2][4];          // O^T frags: lane=q(l16), regs d=dt*16+quad*4+r
    f32x4 lacc[2];          // partial row sums (this lane's k subset)
#pragma unroll
    for (int qh = 0; qh < 2; qh++) {
        lacc[qh] = f32x4{0.f, 0.f, 0.f, 0.f};
#pragma unroll
        for (int dt = 0; dt < 4; dt++) o[qh][dt] = f32x4{0.f, 0.f, 0.f, 0.f};
    }

    const int T = qt + 1;
    const int kr0 = t >> 3, kce = (t & 7) * 8;      // K staging map
    const int vr0 = t >> 4, vce = (t & 15) * 8;     // V staging map

    // prologue staging load (tile 0)
    uint4 k0 = *(const uint4*)(Kg + (size_t)kr0 * DH + kce);
    uint4 k1 = *(const uint4*)(Kg + (size_t)(kr0 + 64) * DH + kce);
    uint4 v0 = *(const uint4*)(Vg + (size_t)vr0 * S_LEN + vce);
    uint4 v1 = *(const uint4*)(Vg + (size_t)(vr0 + 32) * S_LEN + vce);

    for (int kt = 0; kt < T; kt++) {
        __syncthreads();            // previous tile's LDS reads done
        *(uint4*)(Ks + kr0 * 72 + kce) = k0;
        *(uint4*)(Ks + (kr0 + 64) * 72 + kce) = k1;
        *(uint4*)(Vs + vr0 * 136 + vce) = v0;
        *(uint4*)(Vs + (vr0 + 32) * 136 + vce) = v1;
        __syncthreads();            // staged tile visible

        if (kt + 1 < T) {           // T14: issue next tile's loads under compute
            const int kb = (kt + 1) * 128;
            k0 = *(const uint4*)(Kg + (size_t)(kb + kr0) * DH + kce);
            k1 = *(const uint4*)(Kg + (size_t)(kb + kr0 + 64) * DH + kce);
            v0 = *(const uint4*)(Vg + (size_t)vr0 * S_LEN + kb + vce);
            v1 = *(const uint4*)(Vg + (size_t)(vr0 + 32) * S_LEN + kb + vce);
        }

        const bool diag = (kt == qt);

#pragma unroll
        for (int itp = 0; itp < 2; itp++) {
            // ---- S^T = mfma(K, Q): lane holds S[q=l16][k=itg*16+quad*4+r]
            f32x4 p[2][2];
#pragma unroll
            for (int e = 0; e < 2; e++) {
                const int itg = kh * 4 + itp * 2 + e;
                const bf16* kp = Ks + (itg * 16 + l16) * 72 + quad * 8;
                bf16x8 kf0 = *(const bf16x8*)(kp);
                bf16x8 kf1 = *(const bf16x8*)(kp + 32);
#pragma unroll
                for (int qh = 0; qh < 2; qh++) {
                    f32x4 s = __builtin_amdgcn_mfma_f32_16x16x32_bf16(
                        kf0, qf[qh][0], f32x4{0.f, 0.f, 0.f, 0.f}, 0, 0, 0);
                    s = __builtin_amdgcn_mfma_f32_16x16x32_bf16(
                        kf1, qf[qh][1], s, 0, 0, 0);
                    if (diag) {
                        const int kloc = kh * 64 + (itp * 2 + e) * 16 + quad * 4;
                        const int qloc = qs * 32 + qh * 16 + l16;
#pragma unroll
                        for (int r = 0; r < 4; r++)
                            if (kloc + r > qloc) s[r] = NEG_INF;
                    }
                    f32x4 pe;
#pragma unroll
                    for (int r = 0; r < 4; r++) pe[r] = exp2f(s[r]);
                    lacc[qh] += pe;
                    p[qh][e] = pe;
                }
            }

            // ---- P -> B-frag: cvt_pk pairs, then swap32+swap16 places
            // k = quad*8 + {0..7} at each quad (in-register transpose)
            BU bu0, bu1;
            {
                u32 a0 = cvtpk_bf16(p[0][0][0], p[0][0][1]);
                u32 a1 = cvtpk_bf16(p[0][0][2], p[0][0][3]);
                u32 b0 = cvtpk_bf16(p[0][1][0], p[0][1][1]);
                u32 b1 = cvtpk_bf16(p[0][1][2], p[0][1][3]);
                pswap32(a0, b0); pswap16(a0, b0);
                pswap32(a1, b1); pswap16(a1, b1);
                bu0.u[0] = a0; bu0.u[1] = a1; bu0.u[2] = b0; bu0.u[3] = b1;
            }
            {
                u32 a0 = cvtpk_bf16(p[1][0][0], p[1][0][1]);
                u32 a1 = cvtpk_bf16(p[1][0][2], p[1][0][3]);
                u32 b0 = cvtpk_bf16(p[1][1][0], p[1][1][1]);
                u32 b1 = cvtpk_bf16(p[1][1][2], p[1][1][3]);
                pswap32(a0, b0); pswap16(a0, b0);
                pswap32(a1, b1); pswap16(a1, b1);
                bu1.u[0] = a0; bu1.u[1] = a1; bu1.u[2] = b0; bu1.u[3] = b1;
            }

            // ---- O^T += mfma(V^T-frag, P-frag)
            const int ksg = kh * 2 + itp;
#pragma unroll
            for (int dt = 0; dt < 4; dt++) {
                bf16x8 vf = *(const bf16x8*)(Vs + (dt * 16 + l16) * 136 + ksg * 32 + quad * 8);
                o[0][dt] = __builtin_amdgcn_mfma_f32_16x16x32_bf16(vf, bu0.h, o[0][dt], 0, 0, 0);
                o[1][dt] = __builtin_amdgcn_mfma_f32_16x16x32_bf16(vf, bu1.h, o[1][dt], 0, 0, 0);
            }
        }
    }

    // ---- epilogue: quad-reduce l, then cross-k-half O/l reduce via LDS
    float lsum[2];
#pragma unroll
    for (int qh = 0; qh < 2; qh++) {
        float l = lacc[qh][0] + lacc[qh][1] + lacc[qh][2] + lacc[qh][3];
        l += __shfl_xor(l, 16);
        l += __shfl_xor(l, 32);
        lsum[qh] = l;
    }

    __syncthreads();                         // all LDS reads done; reuse smem
    f32x4* Or = (f32x4*)smem;                // 2048 x 16B = 32 KB
    float*  Lr = (float*)(smem + 32768);     // 128 x 4B

    if (kh == 1) {
#pragma unroll
        for (int qh = 0; qh < 2; qh++) {
#pragma unroll
            for (int dt = 0; dt < 4; dt++)
                Or[(((qs * 2 + qh) * 4 + dt) * 4 + quad) * 16 + l16] = o[qh][dt];
            if (quad == 0) Lr[(qs * 2 + qh) * 16 + l16] = lsum[qh];
        }
    }
    __syncthreads();
    if (kh == 0) {
#pragma unroll
        for (int qh = 0; qh < 2; qh++) {
            const float inv = 1.0f / (lsum[qh] + Lr[(qs * 2 + qh) * 16 + l16]);
            const int qg = qrow0 + qh * 16 + l16;
#pragma unroll
            for (int dt = 0; dt < 4; dt++) {
                f32x4 ov = o[qh][dt] + Or[(((qs * 2 + qh) * 4 + dt) * 4 + quad) * 16 + l16];
                bf16x4 w4;
#pragma unroll
                for (int r = 0; r < 4; r++) w4[r] = (bf16)(ov[r] * inv);
                *(bf16x4*)(Og + (size_t)qg * E_DIM + dt * 16 + quad * 4) = w4;
            }
        }
    }
}

// ---------------------------------------------------------------------------
extern "C" void kernel_launch(void* const* d_in, const int* in_sizes, int n_in,
                              void* d_out, int out_size, void* d_ws, size_t ws_size,
                              hipStream_t stream)
{
    const float* x  = (const float*)d_in[0];
    const float* Wq = (const float*)d_in[1];
    const float* bq = (const float*)d_in[2];
    const float* Wk = (const float*)d_in[3];
    const float* bk = (const float*)d_in[4];
    const float* Wv = (const float*)d_in[5];
    const float* bv = (const float*)d_in[6];
    const float* Wo = (const float*)d_in[7];
    const float* bo = (const float*)d_in[8];
    float* out = (float*)d_out;

    char* ws = (char*)d_ws;
    const size_t MB = 1ull << 20;
    bf16* xb  = (bf16*)(ws + 0);        //  8 MB: x   bf16 [4096][1024]
    bf16* wqb = (bf16*)(ws + 8 * MB);   //  2 MB
    bf16* wkb = (bf16*)(ws + 10 * MB);  //  2 MB
    bf16* wvb = (bf16*)(ws + 12 * MB);  //  2 MB
    bf16* wob = (bf16*)(ws + 14 * MB);  //  2 MB
    bf16* Qb  = (bf16*)(ws + 16 * MB);  //  8 MB: [b][h][s][d] (q scaled 0.125*log2e)
    bf16* Kb  = (bf16*)(ws + 24 * MB);  //  8 MB: [b][h][s][d]
    bf16* Vtb = (bf16*)(ws + 32 * MB);  //  8 MB: [b][h][d][s]
    bf16* Ab  = (bf16*)(ws + 40 * MB);  //  8 MB: attn out [b][s][e]

    // 1) fp32 -> bf16 for x and the four weight matrices
    convert_kernel<<<dim3(4096, 5), 256, 0, stream>>>(
        x, Wq, Wk, Wv, Wo, xb, wqb, wkb, wvb, wob, 4194304, 1048576);

    // 2) Q/K/V projections
    gemm_kernel<<<dim3(8, 32, 3), 256, 0, stream>>>(
        xb, wqb, wkb, wvb, bq, bk, bv, Qb, Kb, Vtb, nullptr, 0);

    // 3) causal flash attention (512 blocks, swapped-QK in-register softmax)
    attn_kernel<<<dim3(512), 512, 0, stream>>>(Qb, Kb, Vtb, Ab);

    // 4) output projection -> fp32 d_out
    gemm_kernel<<<dim3(8, 32, 1), 256, 0, stream>>>(
        Ab, wob, wob, wob, bo, bo, bo, nullptr, nullptr, nullptr, out, 1);
}